// Round 3
// 130.328 us; speedup vs baseline: 1.0066x; 1.0066x over previous
//
#include <hip/hip_runtime.h>

constexpr int F = 2048;          // NUM_FEATURES
constexpr int NROWS = 8192;      // rows
constexpr float EPS = 1e-6f;
constexpr int STRIDE4 = F / 4;   // 512 float4 per row

typedef float nfloat4 __attribute__((ext_vector_type(4)));  // native vec for nontemporal builtin

// ---------------------------------------------------------------------------
// Pass 1: per-column partial sum / sumsq.
// Grid (8, 128), block 256. Block covers 64 float4-columns x 64 rows.
// Threads: lc = tid&63 (column), sg = tid>>6 (row subgroup, 16 rows each).
// LDS reduces the 4 subgroups so only 64 threads/block do atomics
// (1024 blocks * 64 thr * 8 atomics = 524k atomic float adds).
// ---------------------------------------------------------------------------
__global__ __launch_bounds__(256) void reduce_kernel(const float* __restrict__ x,
                                                     float* __restrict__ acc) {
    __shared__ float4 lS[3 * 64];
    __shared__ float4 lQ[3 * 64];

    const int lc = threadIdx.x & 63;
    const int sg = threadIdx.x >> 6;
    const int c4 = blockIdx.x * 64 + lc;
    const int row0 = blockIdx.y * 64 + sg * 16;
    const float4* __restrict__ xv = reinterpret_cast<const float4*>(x);

    float4 s = make_float4(0.f, 0.f, 0.f, 0.f);
    float4 q = make_float4(0.f, 0.f, 0.f, 0.f);

    size_t base = (size_t)row0 * STRIDE4 + (size_t)c4;
#pragma unroll
    for (int r = 0; r < 16; ++r) {
        float4 v = xv[base + (size_t)r * STRIDE4];
        s.x += v.x;  s.y += v.y;  s.z += v.z;  s.w += v.w;
        q.x = fmaf(v.x, v.x, q.x);
        q.y = fmaf(v.y, v.y, q.y);
        q.z = fmaf(v.z, v.z, q.z);
        q.w = fmaf(v.w, v.w, q.w);
    }

    if (sg != 0) {
        lS[(sg - 1) * 64 + lc] = s;
        lQ[(sg - 1) * 64 + lc] = q;
    }
    __syncthreads();

    if (sg == 0) {
#pragma unroll
        for (int k = 0; k < 3; ++k) {
            float4 t = lS[k * 64 + lc];
            float4 u = lQ[k * 64 + lc];
            s.x += t.x;  s.y += t.y;  s.z += t.z;  s.w += t.w;
            q.x += u.x;  q.y += u.y;  q.z += u.z;  q.w += u.w;
        }
        float* __restrict__ sum   = acc;
        float* __restrict__ sumsq = acc + F;
        const int c = c4 * 4;
        atomicAdd(&sum[c + 0], s.x);
        atomicAdd(&sum[c + 1], s.y);
        atomicAdd(&sum[c + 2], s.z);
        atomicAdd(&sum[c + 3], s.w);
        atomicAdd(&sumsq[c + 0], q.x);
        atomicAdd(&sumsq[c + 1], q.y);
        atomicAdd(&sumsq[c + 2], q.z);
        atomicAdd(&sumsq[c + 3], q.w);
    }
}

// ---------------------------------------------------------------------------
// Pass 2 (fused finalize + normalize).
// Same geometry as reduce: grid (8, 128), block 256; block covers
// 64 float4-columns x 64 rows, thread (lc, sg) does 16 rows of one f4-column.
// Each thread computes its column's rstd/bias inline from acc (2 float4,
// L2-hot, 8 KB/block with 4x redundancy — negligible), then streams
// out = fma(x, r, b). x re-read is mostly L3-hit (64 MiB << 256 MiB L3);
// out stores are non-temporal so the write stream doesn't evict x from L3.
// ---------------------------------------------------------------------------
__global__ __launch_bounds__(256) void norm_kernel(const float* __restrict__ x,
                                                   const float* __restrict__ acc,
                                                   float* __restrict__ out) {
    const int lc = threadIdx.x & 63;
    const int sg = threadIdx.x >> 6;
    const int c4 = blockIdx.x * 64 + lc;
    const int row0 = blockIdx.y * 64 + sg * 16;
    const float4* __restrict__ xv = reinterpret_cast<const float4*>(x);
    nfloat4* __restrict__ ov      = reinterpret_cast<nfloat4*>(out);

    // Inline finalize for this thread's column.
    const float4 S1 = reinterpret_cast<const float4*>(acc)[c4];
    const float4 S2 = reinterpret_cast<const float4*>(acc + F)[c4];

    const float invN  = 1.0f / (float)NROWS;
    const float invN1 = 1.0f / (float)(NROWS - 1);

    float4 r4, b4;
    {
        const float mx = S1.x * invN;
        const float my = S1.y * invN;
        const float mz = S1.z * invN;
        const float mw = S1.w * invN;
        const float vx = fmaxf((S2.x - S1.x * mx) * invN1, 0.0f);
        const float vy = fmaxf((S2.y - S1.y * my) * invN1, 0.0f);
        const float vz = fmaxf((S2.z - S1.z * mz) * invN1, 0.0f);
        const float vw = fmaxf((S2.w - S1.w * mw) * invN1, 0.0f);
        r4.x = rsqrtf(vx + EPS);
        r4.y = rsqrtf(vy + EPS);
        r4.z = rsqrtf(vz + EPS);
        r4.w = rsqrtf(vw + EPS);
        b4.x = -mx * r4.x;
        b4.y = -my * r4.y;
        b4.z = -mz * r4.z;
        b4.w = -mw * r4.w;
    }

    const size_t base = (size_t)row0 * STRIDE4 + (size_t)c4;
#pragma unroll
    for (int r = 0; r < 16; ++r) {
        const size_t idx = base + (size_t)r * STRIDE4;
        const float4 t = xv[idx];
        nfloat4 o;
        o.x = fmaf(t.x, r4.x, b4.x);
        o.y = fmaf(t.y, r4.y, b4.y);
        o.z = fmaf(t.z, r4.z, b4.z);
        o.w = fmaf(t.w, r4.w, b4.w);
        __builtin_nontemporal_store(o, &ov[idx]);
    }
}

extern "C" void kernel_launch(void* const* d_in, const int* in_sizes, int n_in,
                              void* d_out, int out_size, void* d_ws, size_t ws_size,
                              hipStream_t stream) {
    const float* x = (const float*)d_in[0];
    // running_mean / running_var are wiped by the Welford recurrence (n=1 / n=2).
    float* out = (float*)d_out;
    float* acc = (float*)d_ws;   // [0:F) sum, [F:2F) sumsq

    (void)hipMemsetAsync(d_ws, 0, 2 * F * sizeof(float), stream);

    reduce_kernel<<<dim3(8, NROWS / 64), 256, 0, stream>>>(x, acc);
    norm_kernel<<<dim3(8, NROWS / 64), 256, 0, stream>>>(x, acc, out);
}